// Round 2
// baseline (566.369 us; speedup 1.0000x reference)
//
#include <hip/hip_runtime.h>
#include <hip/hip_bf16.h>

typedef unsigned short u16;
typedef unsigned int u32;
typedef __bf16 bf16x8 __attribute__((ext_vector_type(8)));
typedef float f32x4 __attribute__((ext_vector_type(4)));

// B=65536, I=64, H=64, T=16, G=3H=192

__device__ __forceinline__ u16 f2bf(float f) {
  union { float f; u32 u; } v; v.f = f;
  u32 u = v.u;
  return (u16)((u + 0x7fffu + ((u >> 16) & 1u)) >> 16);  // RNE
}
__device__ __forceinline__ u32 pk2(float a, float b) {
  union { __hip_bfloat162 h; u32 u; } v;
  v.h = __float22bfloat162_rn(float2{a, b});   // v_cvt_pk_bf16_f32 on gfx950
  return v.u;
}
__device__ __forceinline__ bf16x8 pack8(float4 a, float4 b) {
  union { u32 u[4]; bf16x8 v; } r;
  r.u[0] = pk2(a.x, a.y); r.u[1] = pk2(a.z, a.w);
  r.u[2] = pk2(b.x, b.y); r.u[3] = pk2(b.z, b.w);
  return r.v;
}
__device__ __forceinline__ float sigf(float x) { return 1.0f / (1.0f + __expf(-x)); }
__device__ __forceinline__ float tanh_fast(float x) { return 2.0f * sigf(2.0f * x) - 1.0f; }

__device__ __forceinline__ void gl_lds16(const void* g, void* l) {
  __builtin_amdgcn_global_load_lds(
      (const __attribute__((address_space(1))) unsigned int*)g,
      (__attribute__((address_space(3))) unsigned int*)l, 16, 0, 0);
}

// ---------------- K0: weight convert + zero type counters ----------------
__global__ __launch_bounds__(256) void k0_convert(
    const float* __restrict__ Wih, const float* __restrict__ Whh,
    const float* __restrict__ cWih, const float* __restrict__ cWhh,
    u16* __restrict__ wih_bf, u16* __restrict__ whh_bf,
    u16* __restrict__ cwih_bf, u16* __restrict__ cwhh_bf, int* __restrict__ gcnt)
{
  int i = blockIdx.x * 256 + threadIdx.x;
  if (blockIdx.x == 0 && threadIdx.x < 16) gcnt[threadIdx.x] = 0;
  if (i < 196608) {
    wih_bf[i]  = f2bf(Wih[i]);
    whh_bf[i]  = f2bf(Whh[i]);
    cwih_bf[i] = f2bf(cWih[i]);
  }
  if (i < 12288) cwhh_bf[i] = f2bf(cWhh[i]);
}

// ---------------- KC: compact rows by type ----------------
__global__ __launch_bounds__(256) void k_compact(
    const int* __restrict__ typ, int* __restrict__ gcnt, int* __restrict__ lists)
{
  __shared__ int cnt[16], base[16];
  const int tid = threadIdx.x;
  if (tid < 16) cnt[tid] = 0;
  __syncthreads();
  int r = blockIdx.x * 256 + tid;
  int t = typ[r];
  int rank = atomicAdd(&cnt[t], 1);
  __syncthreads();
  if (tid < 16) base[tid] = atomicAdd(&gcnt[tid], cnt[tid]);
  __syncthreads();
  lists[(size_t)t * 65536 + base[t] + rank] = r;
}

// ---------------- K_FUSED: per-type GRU + delta-corrected core GEMM + core GRU ----------------
// Round-2 fixes vs round-1 (which was vmcnt-ordering-poisoned, 12% HBM / 4.7 MfmaUtil):
//  * per chunk: B-fragments (L2) are loaded BEFORE the global_load_lds stage is issued,
//    pinned with sched_barrier(0). Waiting on B now costs only L2 latency; the 4 HBM
//    stage ops stay in flight until the next barrier (true double-buffering).
//  * 3 blocks/CU (launch_bounds(256,3); LDS 41 KB -> 124 KB/CU) for cross-block latency hiding.
//  * grid 48x16 = 768 blocks = exactly 3/CU; grid-stride covers ~64 tiles/type.
__global__ __launch_bounds__(256, 3) void k_fused(
    const float* __restrict__ x, const float* __restrict__ regs,
    const float* __restrict__ c,
    const u16* __restrict__ wih_bf, const u16* __restrict__ whh_bf,
    const float* __restrict__ bih, const float* __restrict__ bhh,
    const u16* __restrict__ cwih_bf, const u16* __restrict__ cwhh_bf,
    const float* __restrict__ cbih, const float* __restrict__ cbhh,
    const int* __restrict__ gcnt, const int* __restrict__ lists,
    float* __restrict__ out)
{
  const int t = blockIdx.y;
  const int cnt = gcnt[t];
  if ((int)blockIdx.x * 64 >= cnt) return;

  __shared__ __align__(16) float sA[2][4096];   // 64 rows x 64 f32, double-buffered (32 KB)
  __shared__ __align__(16) u16  sD[4096];       // 64x64 bf16 delta, group-swizzled (8 KB)
  __shared__ int s_rows[64];

  const int tid = threadIdx.x;
  const int lane = tid & 63;
  const int wv = tid >> 6;
  const int col = lane & 15;
  const int quad = lane >> 4;
  const int hidx = wv * 16 + col;
  const f32x4 zero = {0.f, 0.f, 0.f, 0.f};

  // type-persistent B fragments (L2-hot: shared by all blocks of this type)
  bf16x8 bw[3][2], bh[3][2], bc[3][2];
  float vbi[3], vbh[3];
#pragma unroll
  for (int g = 0; g < 3; ++g) {
    const u16* pw = wih_bf + ((size_t)t * 192 + g * 64 + hidx) * 64;
    const u16* ph = whh_bf + ((size_t)t * 192 + g * 64 + hidx) * 64;
    const u16* pc = cwih_bf + (size_t)(g * 64 + hidx) * 1024 + t * 64;
#pragma unroll
    for (int ks = 0; ks < 2; ++ks) {
      bw[g][ks] = *(const bf16x8*)(pw + ks * 32 + quad * 8);
      bh[g][ks] = *(const bf16x8*)(ph + ks * 32 + quad * 8);
      bc[g][ks] = *(const bf16x8*)(pc + ks * 32 + quad * 8);
    }
    vbi[g] = bih[t * 192 + g * 64 + hidx];
    vbh[g] = bhh[t * 192 + g * 64 + hidx];
  }
  const float e0 = cbih[hidx], e1 = cbih[64 + hidx], e2 = cbih[128 + hidx];
  const float d0 = cbhh[hidx], d1 = cbhh[64 + hidx], d2 = cbhh[128 + hidx];

  for (int tile = blockIdx.x; tile * 64 < cnt; tile += (int)gridDim.x) {
    __syncthreads();   // protect s_rows/sA/sD reuse across tile iterations
    if (tid < 64) {
      int idx = tile * 64 + tid;
      s_rows[tid] = lists[(size_t)t * 65536 + (idx < cnt ? idx : cnt - 1)];
    }
    __syncthreads();

    // per-thread staging base pointers; r = s*16 + wv*4 + quad, so (r&15) is s-invariant
    const int grp = lane & 15;
    const int rsw = wv * 4 + quad;
    const float* pA[4];
#pragma unroll
    for (int s = 0; s < 4; ++s)
      pA[s] = regs + (size_t)s_rows[s * 16 + wv * 4 + quad] * 1024 + ((grp ^ rsw) << 2);

    // stage chunk 0 (latency hides under the GRU head below)
#pragma unroll
    for (int s = 0; s < 4; ++s)
      gl_lds16(pA[s], &sA[0][(s * 4 + wv) * 256]);

    // ---- per-type GRU -> delta tile (bf16, swizzled by 8-element group) ----
#pragma unroll 2
    for (int mt = 0; mt < 4; ++mt) {
      const int ra = s_rows[mt * 16 + col];
      f32x4 agi1[3], agh1[3];
#pragma unroll
      for (int g = 0; g < 3; ++g) { agi1[g] = zero; agh1[g] = zero; }
#pragma unroll
      for (int ks = 0; ks < 2; ++ks) {
        const float* xr = x + (size_t)ra * 64 + ks * 32 + quad * 8;
        const float* hr = regs + (size_t)ra * 1024 + t * 64 + ks * 32 + quad * 8;
        bf16x8 ax = pack8(*(const float4*)xr, *(const float4*)(xr + 4));
        bf16x8 ah = pack8(*(const float4*)hr, *(const float4*)(hr + 4));
#pragma unroll
        for (int g = 0; g < 3; ++g) {
          agi1[g] = __builtin_amdgcn_mfma_f32_16x16x32_bf16(ax, bw[g][ks], agi1[g], 0, 0, 0);
          agh1[g] = __builtin_amdgcn_mfma_f32_16x16x32_bf16(ah, bh[g][ks], agh1[g], 0, 0, 0);
        }
      }
#pragma unroll
      for (int rr = 0; rr < 4; ++rr) {
        const int m = mt * 16 + quad * 4 + rr;
        const int r2 = s_rows[m];
        float ir  = agi1[0][rr] + vbi[0];
        float iz  = agi1[1][rr] + vbi[1];
        float in_ = agi1[2][rr] + vbi[2];
        float hr2 = agh1[0][rr] + vbh[0];
        float hz  = agh1[1][rr] + vbh[1];
        float hn  = agh1[2][rr] + vbh[2];
        float rg = sigf(ir + hr2);
        float zg = sigf(iz + hz);
        float ng = tanh_fast(in_ + rg * hn);
        float hold = regs[(size_t)r2 * 1024 + t * 64 + hidx];
        float hnew = (1.f - zg) * ng + zg * hold;
        sD[m * 64 + (((hidx >> 3) ^ (m & 7)) << 3) + (hidx & 7)] = f2bf(hnew - hold);
      }
    }

    // ---- cgh = c @ cWhh^T (K=64), scattered rows, direct from global ----
    f32x4 agh[4][3];
#pragma unroll
    for (int mt = 0; mt < 4; ++mt)
#pragma unroll
      for (int g = 0; g < 3; ++g) agh[mt][g] = zero;
#pragma unroll
    for (int ks = 0; ks < 2; ++ks) {
      bf16x8 bh2[3];
#pragma unroll
      for (int g = 0; g < 3; ++g)
        bh2[g] = *(const bf16x8*)(cwhh_bf + (size_t)(g * 64 + hidx) * 64 + ks * 32 + quad * 8);
#pragma unroll
      for (int mt = 0; mt < 4; ++mt) {
        const float* cr = c + (size_t)s_rows[mt * 16 + col] * 64 + ks * 32 + quad * 8;
        bf16x8 af = pack8(*(const float4*)cr, *(const float4*)(cr + 4));
#pragma unroll
        for (int g = 0; g < 3; ++g)
          agh[mt][g] = __builtin_amdgcn_mfma_f32_16x16x32_bf16(af, bh2[g], agh[mt][g], 0, 0, 0);
      }
    }

    __syncthreads();   // sD complete; chunk-0 stage drained (compiler vmcnt(0) before barrier)

    // ---- delta-correction chunk: agi += delta @ bc^T (fp32 accumulate) ----
    f32x4 agi[4][3];
#pragma unroll
    for (int mt = 0; mt < 4; ++mt)
#pragma unroll
      for (int g = 0; g < 3; ++g) agi[mt][g] = zero;
#pragma unroll
    for (int ks = 0; ks < 2; ++ks) {
#pragma unroll
      for (int mt = 0; mt < 4; ++mt) {
        const int m = mt * 16 + col;
        bf16x8 ad = *(const bf16x8*)(&sD[m * 64 + (((ks * 4 + quad) ^ (m & 7)) << 3)]);
#pragma unroll
        for (int g = 0; g < 3; ++g)
          agi[mt][g] = __builtin_amdgcn_mfma_f32_16x16x32_bf16(ad, bc[g][ks], agi[mt][g], 0, 0, 0);
      }
    }

    // ---- main GEMM: 16 K-chunks over regs ----
    // Per chunk: B-frags (L2) issued FIRST, then the HBM stage for kc+1.
    // vmcnt waits for B then leave the stage in flight (wait order poison fixed).
    for (int kc = 0; kc < 16; ++kc) {
      __syncthreads();
      bf16x8 bfr[2][3];
#pragma unroll
      for (int ks = 0; ks < 2; ++ks)
#pragma unroll
        for (int g = 0; g < 3; ++g)
          bfr[ks][g] = *(const bf16x8*)(cwih_bf + (size_t)(g * 64 + hidx) * 1024 + kc * 64 + ks * 32 + quad * 8);
      __builtin_amdgcn_sched_barrier(0);   // keep B-frag issue ahead of the stage
      if (kc < 15) {
        float* sAn = sA[(kc + 1) & 1];
#pragma unroll
        for (int s = 0; s < 4; ++s)
          gl_lds16(pA[s] + (kc + 1) * 64, sAn + (s * 4 + wv) * 256);
      }
      __builtin_amdgcn_sched_barrier(0);   // keep stage issue ahead of compute
      const float* sAc = sA[kc & 1];
#pragma unroll
      for (int ks = 0; ks < 2; ++ks) {
#pragma unroll
        for (int mt = 0; mt < 4; ++mt) {
          const int r = mt * 16 + col;
          const int g0 = ks * 8 + quad * 2;
          float4 q0 = *(const float4*)(sAc + r * 64 + (((g0    ) ^ (r & 15)) << 2));
          float4 q1 = *(const float4*)(sAc + r * 64 + (((g0 + 1) ^ (r & 15)) << 2));
          bf16x8 af = pack8(q0, q1);
#pragma unroll
          for (int g = 0; g < 3; ++g)
            agi[mt][g] = __builtin_amdgcn_mfma_f32_16x16x32_bf16(af, bfr[ks][g], agi[mt][g], 0, 0, 0);
        }
      }
    }

    // ---- fused core-GRU epilogue (scattered rows, masked for list padding) ----
#pragma unroll
    for (int mt = 0; mt < 4; ++mt) {
#pragma unroll
      for (int rr = 0; rr < 4; ++rr) {
        const int m = mt * 16 + quad * 4 + rr;
        if (tile * 64 + m < cnt) {
          const size_t b = (size_t)s_rows[m];
          float ir  = agi[mt][0][rr] + e0;
          float iz  = agi[mt][1][rr] + e1;
          float in_ = agi[mt][2][rr] + e2;
          float hr2 = agh[mt][0][rr] + d0;
          float hz  = agh[mt][1][rr] + d1;
          float hn  = agh[mt][2][rr] + d2;
          float rg = sigf(ir + hr2);
          float zg = sigf(iz + hz);
          float ng = tanh_fast(in_ + rg * hn);
          float cold = c[b * 64 + hidx];
          out[b * 64 + hidx] = (1.f - zg) * ng + zg * cold;
        }
      }
    }
  }
}

extern "C" void kernel_launch(void* const* d_in, const int* in_sizes, int n_in,
                              void* d_out, int out_size, void* d_ws, size_t ws_size,
                              hipStream_t stream) {
  const float* x    = (const float*)d_in[0];
  const int*   typ  = (const int*)d_in[1];
  const float* c    = (const float*)d_in[2];
  const float* regs = (const float*)d_in[3];
  const float* Wih  = (const float*)d_in[4];
  const float* Whh  = (const float*)d_in[5];
  const float* bih  = (const float*)d_in[6];
  const float* bhh  = (const float*)d_in[7];
  const float* cWih = (const float*)d_in[8];
  const float* cWhh = (const float*)d_in[9];
  const float* cbih = (const float*)d_in[10];
  const float* cbhh = (const float*)d_in[11];
  float* out = (float*)d_out;

  char* ws = (char*)d_ws;
  u16* wih_bf  = (u16*)(ws + 0);            // 393216 B
  u16* whh_bf  = (u16*)(ws + 393216);       // 393216 B
  u16* cwih_bf = (u16*)(ws + 786432);       // 393216 B
  u16* cwhh_bf = (u16*)(ws + 1179648);      // 24576 B
  int* gcnt    = (int*)(ws + 1204224);      // 64 B
  int* lists   = (int*)(ws + 1204288);      // 4 MB

  k0_convert<<<768, 256, 0, stream>>>(Wih, Whh, cWih, cWhh,
                                      wih_bf, whh_bf, cwih_bf, cwhh_bf, gcnt);
  k_compact<<<256, 256, 0, stream>>>(typ, gcnt, lists);
  // 768 blocks = 3/CU; grid-stride tile loop covers ~64 tiles/type regardless of cnt skew.
  k_fused<<<dim3(48, 16), 256, 0, stream>>>(x, regs, c, wih_bf, whh_bf, bih, bhh,
                                            cwih_bf, cwhh_bf, cbih, cbhh, gcnt, lists, out);
}

// Round 3
// 545.203 us; speedup vs baseline: 1.0388x; 1.0388x over previous
//
#include <hip/hip_runtime.h>
#include <hip/hip_bf16.h>

typedef unsigned short u16;
typedef unsigned int u32;
typedef __bf16 bf16x8 __attribute__((ext_vector_type(8)));
typedef float f32x4 __attribute__((ext_vector_type(4)));

// B=65536, I=64, H=64, T=16, G=3H=192

__device__ __forceinline__ u16 f2bf(float f) {
  union { float f; u32 u; } v; v.f = f;
  u32 u = v.u;
  return (u16)((u + 0x7fffu + ((u >> 16) & 1u)) >> 16);  // RNE
}
__device__ __forceinline__ u32 pk2(float a, float b) {
  union { __hip_bfloat162 h; u32 u; } v;
  v.h = __float22bfloat162_rn(float2{a, b});   // v_cvt_pk_bf16_f32 on gfx950
  return v.u;
}
__device__ __forceinline__ bf16x8 pack8(float4 a, float4 b) {
  union { u32 u[4]; bf16x8 v; } r;
  r.u[0] = pk2(a.x, a.y); r.u[1] = pk2(a.z, a.w);
  r.u[2] = pk2(b.x, b.y); r.u[3] = pk2(b.z, b.w);
  return r.v;
}
__device__ __forceinline__ float sigf(float x) { return 1.0f / (1.0f + __expf(-x)); }
__device__ __forceinline__ float tanh_fast(float x) { return 2.0f * sigf(2.0f * x) - 1.0f; }

__device__ __forceinline__ void gl_lds16(const void* g, void* l) {
  __builtin_amdgcn_global_load_lds(
      (const __attribute__((address_space(1))) unsigned int*)g,
      (__attribute__((address_space(3))) unsigned int*)l, 16, 0, 0);
}

// ---------------- K0: weight convert + zero type counters ----------------
__global__ __launch_bounds__(256) void k0_convert(
    const float* __restrict__ Wih, const float* __restrict__ Whh,
    const float* __restrict__ cWih, const float* __restrict__ cWhh,
    u16* __restrict__ wih_bf, u16* __restrict__ whh_bf,
    u16* __restrict__ cwih_bf, u16* __restrict__ cwhh_bf, int* __restrict__ gcnt)
{
  int i = blockIdx.x * 256 + threadIdx.x;
  if (blockIdx.x == 0 && threadIdx.x < 16) gcnt[threadIdx.x] = 0;
  if (i < 196608) {
    wih_bf[i]  = f2bf(Wih[i]);
    whh_bf[i]  = f2bf(Whh[i]);
    cwih_bf[i] = f2bf(cWih[i]);
  }
  if (i < 12288) cwhh_bf[i] = f2bf(cWhh[i]);
}

// ---------------- KC: compact rows by type ----------------
__global__ __launch_bounds__(256) void k_compact(
    const int* __restrict__ typ, int* __restrict__ gcnt, int* __restrict__ lists)
{
  __shared__ int cnt[16], base[16];
  const int tid = threadIdx.x;
  if (tid < 16) cnt[tid] = 0;
  __syncthreads();
  int r = blockIdx.x * 256 + tid;
  int t = typ[r];
  int rank = atomicAdd(&cnt[t], 1);
  __syncthreads();
  if (tid < 16) base[tid] = atomicAdd(&gcnt[tid], cnt[tid]);
  __syncthreads();
  lists[(size_t)t * 65536 + base[t] + rank] = r;
}

// ---------------- K_FUSED: per-type GRU + delta-corrected core GEMM + core GRU ----------------
// Round-3 fix vs round-2 (which was scratch-spill-poisoned: WRITE_SIZE 166 MB vs out=16.7 MB,
// VGPR capped at 84 by launch_bounds(256,3) against ~200 live regs):
//  * launch_bounds(256,2): register cap 256/wave -> zero spill (round-1 showed 128 VGPR + acc fits).
//  * bw/bh scoped to the GRU-head phase, bc scoped to the correction phase, shrinking live ranges.
//  * grid 32x16 = 512 blocks (2/CU), 2 tiles/block, balanced; grid-stride covers count skew.
// Keeps round-2's issue-order fix (B-frags before the HBM stage, sched_barrier pins) so the
// double-buffered global_load_lds prefetch stays in flight across the compute phase.
__global__ __launch_bounds__(256, 2) void k_fused(
    const float* __restrict__ x, const float* __restrict__ regs,
    const float* __restrict__ c,
    const u16* __restrict__ wih_bf, const u16* __restrict__ whh_bf,
    const float* __restrict__ bih, const float* __restrict__ bhh,
    const u16* __restrict__ cwih_bf, const u16* __restrict__ cwhh_bf,
    const float* __restrict__ cbih, const float* __restrict__ cbhh,
    const int* __restrict__ gcnt, const int* __restrict__ lists,
    float* __restrict__ out)
{
  const int t = blockIdx.y;
  const int cnt = gcnt[t];
  if ((int)blockIdx.x * 64 >= cnt) return;

  __shared__ __align__(16) float sA[2][4096];   // 64 rows x 64 f32, double-buffered (32 KB)
  __shared__ __align__(16) u16  sD[4096];       // 64x64 bf16 delta, group-swizzled (8 KB)
  __shared__ int s_rows[64];

  const int tid = threadIdx.x;
  const int lane = tid & 63;
  const int wv = tid >> 6;
  const int col = lane & 15;
  const int quad = lane >> 4;
  const int hidx = wv * 16 + col;
  const f32x4 zero = {0.f, 0.f, 0.f, 0.f};

  // small persistent per-thread state only (12 bias scalars)
  float vbi[3], vbh[3];
#pragma unroll
  for (int g = 0; g < 3; ++g) {
    vbi[g] = bih[t * 192 + g * 64 + hidx];
    vbh[g] = bhh[t * 192 + g * 64 + hidx];
  }
  const float e0 = cbih[hidx], e1 = cbih[64 + hidx], e2 = cbih[128 + hidx];
  const float d0 = cbhh[hidx], d1 = cbhh[64 + hidx], d2 = cbhh[128 + hidx];

  for (int tile = blockIdx.x; tile * 64 < cnt; tile += (int)gridDim.x) {
    __syncthreads();   // protect s_rows/sA/sD reuse across tile iterations
    if (tid < 64) {
      int idx = tile * 64 + tid;
      s_rows[tid] = lists[(size_t)t * 65536 + (idx < cnt ? idx : cnt - 1)];
    }
    __syncthreads();

    // per-thread staging base pointers; LDS row R = s*16 + wv*4 + quad, (R&15) = wv*4+quad
    const int grp = lane & 15;
    const int rsw = wv * 4 + quad;
    const float* pA[4];
#pragma unroll
    for (int s = 0; s < 4; ++s)
      pA[s] = regs + (size_t)s_rows[s * 16 + wv * 4 + quad] * 1024 + ((grp ^ rsw) << 2);

    // stage chunk 0 (latency hides under the GRU head below)
#pragma unroll
    for (int s = 0; s < 4; ++s)
      gl_lds16(pA[s], &sA[0][(s * 4 + wv) * 256]);

    // ---- per-type GRU -> delta tile (bf16, swizzled by 8-element group) ----
    {
      bf16x8 bw[3][2], bh[3][2];   // phase-local: live only through the head
#pragma unroll
      for (int g = 0; g < 3; ++g) {
        const u16* pw = wih_bf + ((size_t)t * 192 + g * 64 + hidx) * 64;
        const u16* ph = whh_bf + ((size_t)t * 192 + g * 64 + hidx) * 64;
#pragma unroll
        for (int ks = 0; ks < 2; ++ks) {
          bw[g][ks] = *(const bf16x8*)(pw + ks * 32 + quad * 8);
          bh[g][ks] = *(const bf16x8*)(ph + ks * 32 + quad * 8);
        }
      }
#pragma unroll 2
      for (int mt = 0; mt < 4; ++mt) {
        const int ra = s_rows[mt * 16 + col];
        f32x4 agi1[3], agh1[3];
#pragma unroll
        for (int g = 0; g < 3; ++g) { agi1[g] = zero; agh1[g] = zero; }
#pragma unroll
        for (int ks = 0; ks < 2; ++ks) {
          const float* xr = x + (size_t)ra * 64 + ks * 32 + quad * 8;
          const float* hr = regs + (size_t)ra * 1024 + t * 64 + ks * 32 + quad * 8;
          bf16x8 ax = pack8(*(const float4*)xr, *(const float4*)(xr + 4));
          bf16x8 ah = pack8(*(const float4*)hr, *(const float4*)(hr + 4));
#pragma unroll
          for (int g = 0; g < 3; ++g) {
            agi1[g] = __builtin_amdgcn_mfma_f32_16x16x32_bf16(ax, bw[g][ks], agi1[g], 0, 0, 0);
            agh1[g] = __builtin_amdgcn_mfma_f32_16x16x32_bf16(ah, bh[g][ks], agh1[g], 0, 0, 0);
          }
        }
#pragma unroll
        for (int rr = 0; rr < 4; ++rr) {
          const int m = mt * 16 + quad * 4 + rr;
          const int r2 = s_rows[m];
          float ir  = agi1[0][rr] + vbi[0];
          float iz  = agi1[1][rr] + vbi[1];
          float in_ = agi1[2][rr] + vbi[2];
          float hr2 = agh1[0][rr] + vbh[0];
          float hz  = agh1[1][rr] + vbh[1];
          float hn  = agh1[2][rr] + vbh[2];
          float rg = sigf(ir + hr2);
          float zg = sigf(iz + hz);
          float ng = tanh_fast(in_ + rg * hn);
          float hold = regs[(size_t)r2 * 1024 + t * 64 + hidx];
          float hnew = (1.f - zg) * ng + zg * hold;
          sD[m * 64 + (((hidx >> 3) ^ (m & 7)) << 3) + (hidx & 7)] = f2bf(hnew - hold);
        }
      }
    }

    // ---- cgh = c @ cWhh^T (K=64), scattered rows, direct from global ----
    f32x4 agh[4][3];
#pragma unroll
    for (int mt = 0; mt < 4; ++mt)
#pragma unroll
      for (int g = 0; g < 3; ++g) agh[mt][g] = zero;
#pragma unroll
    for (int ks = 0; ks < 2; ++ks) {
      bf16x8 bh2[3];
#pragma unroll
      for (int g = 0; g < 3; ++g)
        bh2[g] = *(const bf16x8*)(cwhh_bf + (size_t)(g * 64 + hidx) * 64 + ks * 32 + quad * 8);
#pragma unroll
      for (int mt = 0; mt < 4; ++mt) {
        const float* cr = c + (size_t)s_rows[mt * 16 + col] * 64 + ks * 32 + quad * 8;
        bf16x8 af = pack8(*(const float4*)cr, *(const float4*)(cr + 4));
#pragma unroll
        for (int g = 0; g < 3; ++g)
          agh[mt][g] = __builtin_amdgcn_mfma_f32_16x16x32_bf16(af, bh2[g], agh[mt][g], 0, 0, 0);
      }
    }

    __syncthreads();   // sD complete; chunk-0 stage drained (compiler vmcnt(0) before barrier)

    // ---- delta-correction chunk: agi += delta @ bc^T (fp32 accumulate) ----
    f32x4 agi[4][3];
#pragma unroll
    for (int mt = 0; mt < 4; ++mt)
#pragma unroll
      for (int g = 0; g < 3; ++g) agi[mt][g] = zero;
    {
      bf16x8 bc[3][2];   // phase-local
#pragma unroll
      for (int g = 0; g < 3; ++g) {
        const u16* pc = cwih_bf + (size_t)(g * 64 + hidx) * 1024 + t * 64;
#pragma unroll
        for (int ks = 0; ks < 2; ++ks)
          bc[g][ks] = *(const bf16x8*)(pc + ks * 32 + quad * 8);
      }
#pragma unroll
      for (int ks = 0; ks < 2; ++ks) {
#pragma unroll
        for (int mt = 0; mt < 4; ++mt) {
          const int m = mt * 16 + col;
          bf16x8 ad = *(const bf16x8*)(&sD[m * 64 + (((ks * 4 + quad) ^ (m & 7)) << 3)]);
#pragma unroll
          for (int g = 0; g < 3; ++g)
            agi[mt][g] = __builtin_amdgcn_mfma_f32_16x16x32_bf16(ad, bc[g][ks], agi[mt][g], 0, 0, 0);
        }
      }
    }

    // ---- main GEMM: 16 K-chunks over regs ----
    // Per chunk: B-frags (L2) issued FIRST, then the HBM stage for kc+1,
    // so the wait for B leaves the 4 stage ops in flight.
    for (int kc = 0; kc < 16; ++kc) {
      __syncthreads();
      bf16x8 bfr[2][3];
#pragma unroll
      for (int ks = 0; ks < 2; ++ks)
#pragma unroll
        for (int g = 0; g < 3; ++g)
          bfr[ks][g] = *(const bf16x8*)(cwih_bf + (size_t)(g * 64 + hidx) * 1024 + kc * 64 + ks * 32 + quad * 8);
      __builtin_amdgcn_sched_barrier(0);   // keep B-frag issue ahead of the stage
      if (kc < 15) {
        float* sAn = sA[(kc + 1) & 1];
#pragma unroll
        for (int s = 0; s < 4; ++s)
          gl_lds16(pA[s] + (kc + 1) * 64, sAn + (s * 4 + wv) * 256);
      }
      __builtin_amdgcn_sched_barrier(0);   // keep stage issue ahead of compute
      const float* sAc = sA[kc & 1];
#pragma unroll
      for (int ks = 0; ks < 2; ++ks) {
#pragma unroll
        for (int mt = 0; mt < 4; ++mt) {
          const int r = mt * 16 + col;
          const int g0 = ks * 8 + quad * 2;
          float4 q0 = *(const float4*)(sAc + r * 64 + (((g0    ) ^ (r & 15)) << 2));
          float4 q1 = *(const float4*)(sAc + r * 64 + (((g0 + 1) ^ (r & 15)) << 2));
          bf16x8 af = pack8(q0, q1);
#pragma unroll
          for (int g = 0; g < 3; ++g)
            agi[mt][g] = __builtin_amdgcn_mfma_f32_16x16x32_bf16(af, bfr[ks][g], agi[mt][g], 0, 0, 0);
        }
      }
    }

    // ---- fused core-GRU epilogue (scattered rows, masked for list padding) ----
#pragma unroll
    for (int mt = 0; mt < 4; ++mt) {
#pragma unroll
      for (int rr = 0; rr < 4; ++rr) {
        const int m = mt * 16 + quad * 4 + rr;
        if (tile * 64 + m < cnt) {
          const size_t b = (size_t)s_rows[m];
          float ir  = agi[mt][0][rr] + e0;
          float iz  = agi[mt][1][rr] + e1;
          float in_ = agi[mt][2][rr] + e2;
          float hr2 = agh[mt][0][rr] + d0;
          float hz  = agh[mt][1][rr] + d1;
          float hn  = agh[mt][2][rr] + d2;
          float rg = sigf(ir + hr2);
          float zg = sigf(iz + hz);
          float ng = tanh_fast(in_ + rg * hn);
          float cold = c[b * 64 + hidx];
          out[b * 64 + hidx] = (1.f - zg) * ng + zg * cold;
        }
      }
    }
  }
}

extern "C" void kernel_launch(void* const* d_in, const int* in_sizes, int n_in,
                              void* d_out, int out_size, void* d_ws, size_t ws_size,
                              hipStream_t stream) {
  const float* x    = (const float*)d_in[0];
  const int*   typ  = (const int*)d_in[1];
  const float* c    = (const float*)d_in[2];
  const float* regs = (const float*)d_in[3];
  const float* Wih  = (const float*)d_in[4];
  const float* Whh  = (const float*)d_in[5];
  const float* bih  = (const float*)d_in[6];
  const float* bhh  = (const float*)d_in[7];
  const float* cWih = (const float*)d_in[8];
  const float* cWhh = (const float*)d_in[9];
  const float* cbih = (const float*)d_in[10];
  const float* cbhh = (const float*)d_in[11];
  float* out = (float*)d_out;

  char* ws = (char*)d_ws;
  u16* wih_bf  = (u16*)(ws + 0);            // 393216 B
  u16* whh_bf  = (u16*)(ws + 393216);       // 393216 B
  u16* cwih_bf = (u16*)(ws + 786432);       // 393216 B
  u16* cwhh_bf = (u16*)(ws + 1179648);      // 24576 B
  int* gcnt    = (int*)(ws + 1204224);      // 64 B
  int* lists   = (int*)(ws + 1204288);      // 4 MB

  k0_convert<<<768, 256, 0, stream>>>(Wih, Whh, cWih, cWhh,
                                      wih_bf, whh_bf, cwih_bf, cwhh_bf, gcnt);
  k_compact<<<256, 256, 0, stream>>>(typ, gcnt, lists);
  // 512 blocks = 2/CU minimum residency; 2 tiles/block; grid-stride covers count skew.
  k_fused<<<dim3(32, 16), 256, 0, stream>>>(x, regs, c, wih_bf, whh_bf, bih, bhh,
                                            cwih_bf, cwhh_bf, cbih, cbhh, gcnt, lists, out);
}

// Round 4
// 467.760 us; speedup vs baseline: 1.2108x; 1.1656x over previous
//
#include <hip/hip_runtime.h>
#include <hip/hip_bf16.h>

typedef unsigned short u16;
typedef unsigned int u32;
typedef __bf16 bf16x8 __attribute__((ext_vector_type(8)));
typedef float f32x4 __attribute__((ext_vector_type(4)));

// B=65536, I=64, H=64, T=16, G=3H=192

__device__ __forceinline__ u16 f2bf(float f) {
  union { float f; u32 u; } v; v.f = f;
  u32 u = v.u;
  return (u16)((u + 0x7fffu + ((u >> 16) & 1u)) >> 16);  // RNE
}
__device__ __forceinline__ u32 pk2(float a, float b) {
  union { __hip_bfloat162 h; u32 u; } v;
  v.h = __float22bfloat162_rn(float2{a, b});   // v_cvt_pk_bf16_f32 on gfx950
  return v.u;
}
__device__ __forceinline__ bf16x8 pack8(float4 a, float4 b) {
  union { u32 u[4]; bf16x8 v; } r;
  r.u[0] = pk2(a.x, a.y); r.u[1] = pk2(a.z, a.w);
  r.u[2] = pk2(b.x, b.y); r.u[3] = pk2(b.z, b.w);
  return r.v;
}
__device__ __forceinline__ float sigf(float x) { return 1.0f / (1.0f + __expf(-x)); }
__device__ __forceinline__ float tanh_fast(float x) { return 2.0f * sigf(2.0f * x) - 1.0f; }

__device__ __forceinline__ void gl_lds16(const void* g, void* l) {
  __builtin_amdgcn_global_load_lds(
      (const __attribute__((address_space(1))) unsigned int*)g,
      (__attribute__((address_space(3))) unsigned int*)l, 16, 0, 0);
}

// ---------------- K0: weight convert + zero type counters ----------------
__global__ __launch_bounds__(256) void k0_convert(
    const float* __restrict__ Wih, const float* __restrict__ Whh,
    const float* __restrict__ cWih, const float* __restrict__ cWhh,
    u16* __restrict__ wih_bf, u16* __restrict__ whh_bf,
    u16* __restrict__ cwih_bf, u16* __restrict__ cwhh_bf, int* __restrict__ gcnt)
{
  int i = blockIdx.x * 256 + threadIdx.x;
  if (blockIdx.x == 0 && threadIdx.x < 16) gcnt[threadIdx.x] = 0;
  if (i < 196608) {
    wih_bf[i]  = f2bf(Wih[i]);
    whh_bf[i]  = f2bf(Whh[i]);
    cwih_bf[i] = f2bf(cWih[i]);
  }
  if (i < 12288) cwhh_bf[i] = f2bf(cWhh[i]);
}

// ---------------- KC: compact rows by type ----------------
__global__ __launch_bounds__(256) void k_compact(
    const int* __restrict__ typ, int* __restrict__ gcnt, int* __restrict__ lists)
{
  __shared__ int cnt[16], base[16];
  const int tid = threadIdx.x;
  if (tid < 16) cnt[tid] = 0;
  __syncthreads();
  int r = blockIdx.x * 256 + tid;
  int t = typ[r];
  int rank = atomicAdd(&cnt[t], 1);
  __syncthreads();
  if (tid < 16) base[tid] = atomicAdd(&gcnt[tid], cnt[tid]);
  __syncthreads();
  lists[(size_t)t * 65536 + base[t] + rank] = r;
}

// ---------------- K1: per-type GRU -> modslot (f32 hnew rows) ----------------
// Rounds 1-3 lesson: fusing forced the 268-MB regs stream through type-sorted
// (random 256-B granule) reads -> tRC-bound ~1 TB/s, 250 us. Split again:
// k1 confines ALL scatter to ~50 MB (x + slot reads, modslot writes); no second
// GEMM, no corr round-trip -- k2 consumes hnew directly via per-lane source select.
__global__ __launch_bounds__(256, 2) void k1_gru(
    const float* __restrict__ x, const float* __restrict__ regs,
    const u16* __restrict__ wih_bf, const u16* __restrict__ whh_bf,
    const float* __restrict__ bih, const float* __restrict__ bhh,
    const int* __restrict__ gcnt, const int* __restrict__ lists,
    float* __restrict__ modslot)
{
  const int t = blockIdx.y;
  const int cnt = gcnt[t];
  const int ntiles = (cnt + 15) >> 4;

  const int tid = threadIdx.x;
  const int lane = tid & 63;
  const int w = tid >> 6;
  const int col = lane & 15;
  const int quad = lane >> 4;
  const int hidx = w * 16 + col;
  const f32x4 zero = {0.f, 0.f, 0.f, 0.f};

  // persistent B fragments (L2-hot, shared by all blocks of this type)
  bf16x8 bw[3][2], bh[3][2];
  float vbi[3], vbh[3];
#pragma unroll
  for (int g = 0; g < 3; ++g) {
    const u16* pw = wih_bf + ((size_t)t * 192 + g * 64 + hidx) * 64;
    const u16* ph = whh_bf + ((size_t)t * 192 + g * 64 + hidx) * 64;
#pragma unroll
    for (int ks = 0; ks < 2; ++ks) {
      bw[g][ks] = *(const bf16x8*)(pw + ks * 32 + quad * 8);
      bh[g][ks] = *(const bf16x8*)(ph + ks * 32 + quad * 8);
    }
    vbi[g] = bih[t * 192 + g * 64 + hidx];
    vbh[g] = bhh[t * 192 + g * 64 + hidx];
  }

  __shared__ int s_rows[16];

  for (int tile = blockIdx.x; tile < ntiles; tile += 32) {
    __syncthreads();
    if (tid < 16) {
      int idx = tile * 16 + tid;
      s_rows[tid] = lists[(size_t)t * 65536 + (idx < cnt ? idx : cnt - 1)];
    }
    __syncthreads();

    const int ra = s_rows[col];   // A-row for this lane's m index
    f32x4 agi[3], agh[3];
#pragma unroll
    for (int g = 0; g < 3; ++g) { agi[g] = zero; agh[g] = zero; }
#pragma unroll
    for (int ks = 0; ks < 2; ++ks) {
      const float* xr = x + (size_t)ra * 64 + ks * 32 + quad * 8;
      const float* hr = regs + (size_t)ra * 1024 + t * 64 + ks * 32 + quad * 8;
      bf16x8 ax = pack8(*(const float4*)xr, *(const float4*)(xr + 4));
      bf16x8 ah = pack8(*(const float4*)hr, *(const float4*)(hr + 4));
#pragma unroll
      for (int g = 0; g < 3; ++g) {
        agi[g] = __builtin_amdgcn_mfma_f32_16x16x32_bf16(ax, bw[g][ks], agi[g], 0, 0, 0);
        agh[g] = __builtin_amdgcn_mfma_f32_16x16x32_bf16(ah, bh[g][ks], agh[g], 0, 0, 0);
      }
    }
    // epilogue: hnew -> modslot (f32, full 64-col row across the 4 waves)
#pragma unroll
    for (int rr = 0; rr < 4; ++rr) {
      int m = quad * 4 + rr;
      if (tile * 16 + m < cnt) {
        int r2 = s_rows[m];
        float ir  = agi[0][rr] + vbi[0];
        float iz  = agi[1][rr] + vbi[1];
        float in_ = agi[2][rr] + vbi[2];
        float hr  = agh[0][rr] + vbh[0];
        float hz  = agh[1][rr] + vbh[1];
        float hn  = agh[2][rr] + vbh[2];
        float rg = sigf(ir + hr);
        float zg = sigf(iz + hz);
        float ng = tanh_fast(in_ + rg * hn);
        float hold = regs[(size_t)r2 * 1024 + t * 64 + hidx];
        float hnew = (1.f - zg) * ng + zg * hold;
        modslot[(size_t)r2 * 64 + hidx] = hnew;
      }
    }
  }
}

// ---------------- K2: streaming GEMM + core GRU ----------------
// 64 CONTIGUOUS rows/block, grid 1024, 16 K-chunks of 64, double-buffered
// global_load_lds, XOR-swizzled LDS (swizzle on the per-lane GLOBAL address).
// reg_new realized at stage time: rows with typ[row]==kc source chunk kc from
// modslot (per-lane source address select) -- no correction GEMM, no corr buffer.
__global__ __launch_bounds__(256, 2) void k2_core(
    const float* __restrict__ regs, const float* __restrict__ c,
    const int* __restrict__ typ, const float* __restrict__ modslot,
    const u16* __restrict__ cwih_bf, const u16* __restrict__ cwhh_bf,
    const float* __restrict__ cbih, const float* __restrict__ cbhh,
    float* __restrict__ out)
{
  __shared__ __align__(16) float sA[2][4096];   // 64 rows x 64 f32, 16 KB each
  __shared__ __align__(16) u16  sB[2][12288];   // 192 rows x 64 bf16, 24 KB each

  const int tid = threadIdx.x;
  const int b0 = blockIdx.x * 64;
  const int lane = tid & 63;
  const int wv = tid >> 6;
  const int col = lane & 15;
  const int quad = lane >> 4;
  const int hidx = wv * 16 + col;
  const f32x4 zero = {0.f, 0.f, 0.f, 0.f};

  // per-thread A-staging state: 4 rows, regs/modslot base pointers + row type
  const int grp = lane & 15;
  const float* pA[4];
  const float* pM[4];
  int t4[4];
#pragma unroll
  for (int s = 0; s < 4; ++s) {
    int i = s * 4 + wv;
    int r = i * 4 + (lane >> 4);
    int swz = (grp ^ (r & 15)) << 2;
    pA[s] = regs + (size_t)(b0 + r) * 1024 + swz;
    pM[s] = modslot + (size_t)(b0 + r) * 64 + swz;
    t4[s] = typ[b0 + r];
  }

  // --- stage chunk 0 ---
  {
#pragma unroll
    for (int s = 0; s < 4; ++s) {
      const float* src = (t4[s] == 0) ? pM[s] : pA[s];
      gl_lds16(src, &sA[0][(s * 4 + wv) * 256]);
    }
#pragma unroll
    for (int s = 0; s < 6; ++s) {
      int j = s * 4 + wv;
      int n = j * 8 + (lane >> 3);
      int grpb = lane & 7;
      gl_lds16(cwih_bf + (size_t)n * 1024 + ((grpb ^ (n & 7)) << 3), &sB[0][j * 512]);
    }
  }

  // --- cgh = c @ cWhh^T (K=64), direct from global, overlaps stage-0 latency ---
  f32x4 agh[4][3];
#pragma unroll
  for (int mt = 0; mt < 4; ++mt)
#pragma unroll
    for (int g = 0; g < 3; ++g) agh[mt][g] = zero;
#pragma unroll
  for (int ks = 0; ks < 2; ++ks) {
    bf16x8 bh2[3];
#pragma unroll
    for (int g = 0; g < 3; ++g)
      bh2[g] = *(const bf16x8*)(cwhh_bf + (size_t)(g * 64 + hidx) * 64 + ks * 32 + quad * 8);
#pragma unroll
    for (int mt = 0; mt < 4; ++mt) {
      const float* cr = c + (size_t)(b0 + mt * 16 + col) * 64 + ks * 32 + quad * 8;
      bf16x8 af = pack8(*(const float4*)cr, *(const float4*)(cr + 4));
#pragma unroll
      for (int g = 0; g < 3; ++g)
        agh[mt][g] = __builtin_amdgcn_mfma_f32_16x16x32_bf16(af, bh2[g], agh[mt][g], 0, 0, 0);
    }
  }

  // --- main K-loop ---
  f32x4 agi[4][3];
#pragma unroll
  for (int mt = 0; mt < 4; ++mt)
#pragma unroll
    for (int g = 0; g < 3; ++g) agi[mt][g] = zero;

  for (int kc = 0; kc < 16; ++kc) {
    __syncthreads();   // drains stage of current buffer; prior reads of next buffer done
    if (kc < 15) {
      float* sAn = sA[(kc + 1) & 1];
      u16*   sBn = sB[(kc + 1) & 1];
#pragma unroll
      for (int s = 0; s < 4; ++s) {
        const float* src = (t4[s] == kc + 1) ? pM[s] : (pA[s] + (kc + 1) * 64);
        gl_lds16(src, sAn + (s * 4 + wv) * 256);
      }
#pragma unroll
      for (int s = 0; s < 6; ++s) {
        int j = s * 4 + wv;
        int n = j * 8 + (lane >> 3);
        int grpb = lane & 7;
        gl_lds16(cwih_bf + (size_t)n * 1024 + (kc + 1) * 64 + ((grpb ^ (n & 7)) << 3),
                 sBn + j * 512);
      }
    }
    const float* sAc = sA[kc & 1];
    const u16*   sBc = sB[kc & 1];
#pragma unroll
    for (int ks = 0; ks < 2; ++ks) {
      bf16x8 bfr[3];
#pragma unroll
      for (int g = 0; g < 3; ++g) {
        int n = g * 64 + hidx;
        int grpb = ks * 4 + quad;
        bfr[g] = *(const bf16x8*)(sBc + n * 64 + ((grpb ^ (n & 7)) << 3));
      }
#pragma unroll
      for (int mt = 0; mt < 4; ++mt) {
        int r = mt * 16 + col;
        int g0 = ks * 8 + quad * 2;
        float4 q0 = *(const float4*)(sAc + r * 64 + (((g0    ) ^ (r & 15)) << 2));
        float4 q1 = *(const float4*)(sAc + r * 64 + (((g0 + 1) ^ (r & 15)) << 2));
        bf16x8 af = pack8(q0, q1);
#pragma unroll
        for (int g = 0; g < 3; ++g)
          agi[mt][g] = __builtin_amdgcn_mfma_f32_16x16x32_bf16(af, bfr[g], agi[mt][g], 0, 0, 0);
      }
    }
  }

  // --- fused core-GRU epilogue ---
  float e0 = cbih[hidx], e1 = cbih[64 + hidx], e2 = cbih[128 + hidx];
  float d0 = cbhh[hidx], d1 = cbhh[64 + hidx], d2 = cbhh[128 + hidx];
#pragma unroll
  for (int mt = 0; mt < 4; ++mt) {
#pragma unroll
    for (int rr = 0; rr < 4; ++rr) {
      int row = mt * 16 + quad * 4 + rr;
      size_t b = (size_t)(b0 + row);
      float ir  = agi[mt][0][rr] + e0;
      float iz  = agi[mt][1][rr] + e1;
      float in_ = agi[mt][2][rr] + e2;
      float hr  = agh[mt][0][rr] + d0;
      float hz  = agh[mt][1][rr] + d1;
      float hn  = agh[mt][2][rr] + d2;
      float rg = sigf(ir + hr);
      float zg = sigf(iz + hz);
      float ng = tanh_fast(in_ + rg * hn);
      float cold = c[b * 64 + hidx];
      out[b * 64 + hidx] = (1.f - zg) * ng + zg * cold;
    }
  }
}

extern "C" void kernel_launch(void* const* d_in, const int* in_sizes, int n_in,
                              void* d_out, int out_size, void* d_ws, size_t ws_size,
                              hipStream_t stream) {
  const float* x    = (const float*)d_in[0];
  const int*   typ  = (const int*)d_in[1];
  const float* c    = (const float*)d_in[2];
  const float* regs = (const float*)d_in[3];
  const float* Wih  = (const float*)d_in[4];
  const float* Whh  = (const float*)d_in[5];
  const float* bih  = (const float*)d_in[6];
  const float* bhh  = (const float*)d_in[7];
  const float* cWih = (const float*)d_in[8];
  const float* cWhh = (const float*)d_in[9];
  const float* cbih = (const float*)d_in[10];
  const float* cbhh = (const float*)d_in[11];
  float* out = (float*)d_out;

  char* ws = (char*)d_ws;
  u16* wih_bf  = (u16*)(ws + 0);            // 393216 B
  u16* whh_bf  = (u16*)(ws + 393216);       // 393216 B
  u16* cwih_bf = (u16*)(ws + 786432);       // 393216 B
  u16* cwhh_bf = (u16*)(ws + 1179648);      // 24576 B
  int* gcnt    = (int*)(ws + 1204224);      // 64 B
  int* lists   = (int*)(ws + 1204288);      // 4 MB
  float* modslot = (float*)(ws + 5398592);  // 16777216 B (B x 64 f32 hnew rows)

  k0_convert<<<768, 256, 0, stream>>>(Wih, Whh, cWih, cWhh,
                                      wih_bf, whh_bf, cwih_bf, cwhh_bf, gcnt);
  k_compact<<<256, 256, 0, stream>>>(typ, gcnt, lists);
  k1_gru<<<dim3(32, 16), 256, 0, stream>>>(x, regs, wih_bf, whh_bf, bih, bhh,
                                           gcnt, lists, modslot);
  k2_core<<<1024, 256, 0, stream>>>(regs, c, typ, modslot, cwih_bf, cwhh_bf,
                                    cbih, cbhh, out);
}